// Round 4
// baseline (570.922 us; speedup 1.0000x reference)
//
#include <hip/hip_runtime.h>
#include <math.h>

typedef float f32x4 __attribute__((ext_vector_type(4)));

// ---------------------------------------------------------------------------
// R15: split architecture (proven in R12) x light compute (proven in R14).
//
// Decomposition from measured rounds:
//   R12 557 = fill(349) + k_mlp_heavy(~120) + k_bcast(~88)   [split correct]
//   R14 560 = fill(344) + fused_light(~215)                  [fused store slow]
// -> the untried cell is {split, light}: predicted kernel side ~110 us.
//
// k_mlp_lite: 2048 blocks x 64 threads (1 wave), R14's compute verbatim
//   (no weight staging, rows straight from L2; freq/sincos/FMA order
//   bitwise-identical to R11/R14 -> same absmax). Tail writes ONLY h2 into
//   row 0 of each of its 4 images (2 store instrs/wave, 4 MB device-wide).
//
// k_bcast: R12's proven memset-shaped broadcast: 1 block per image, read
//   row 0 (L2-hit; kernel-boundary flush guarantees visibility), write rows
//   1..127, row 0 skipped (no race). Fill demonstrates 6.3 TB/s on this
//   stream shape -> ~88 us.
//
// If this is flat vs R14 again, the residual is a fixed harness floor and
// the kernel side is at the 537 MB write roofline.
// ---------------------------------------------------------------------------
__global__ __launch_bounds__(64) void k_mlp_lite(
    const float* __restrict__ t,
    const float* __restrict__ W1, const float* __restrict__ b1,
    const float* __restrict__ W2, const float* __restrict__ b2,
    float* __restrict__ out)
{
    __shared__ __attribute__((aligned(16))) float E [4 * 128]; // emb -> h2
    __shared__ __attribute__((aligned(16))) float H1[4 * 128];

    const int l    = threadIdx.x;        // lane 0..63
    const int base = blockIdx.x * 4;     // 4 batches per wave

    // ---- embedding: lane l owns freq l; 4 batches ----
    {
        double a   = (double)l * (6.907755278982137 / 63.0);
        float freq = (float)exp(a);
        float ang  = 6.2831853071795865f * freq;
        #pragma unroll
        for (int b = 0; b < 4; ++b) {
            float ph = t[base + b] * ang;
            float sv, cv;
            sincosf(ph, &sv, &cv);
            E[b * 128 + l]      = sv;
            E[b * 128 + 64 + l] = cv;
        }
    }
    __syncthreads();   // 1-wave block: waitcnt only

    // ---- layer 1: neurons r0=l, r1=l+64 over 4 batches ----
    {
        const f32x4* w0 = (const f32x4*)(W1 + l * 128);
        const f32x4* w1 = (const f32x4*)(W1 + (l + 64) * 128);
        float acc[2][4];
        float bv0 = b1[l], bv1 = b1[l + 64];
        #pragma unroll
        for (int b = 0; b < 4; ++b) { acc[0][b] = bv0; acc[1][b] = bv1; }
        #pragma unroll 8
        for (int k4 = 0; k4 < 32; ++k4) {
            f32x4 wa = w0[k4];
            f32x4 wb = w1[k4];
            #pragma unroll
            for (int b = 0; b < 4; ++b) {
                f32x4 ev = ((const f32x4*)(E + b * 128))[k4];  // LDS broadcast
                acc[0][b] = fmaf(wa.x, ev.x, acc[0][b]);
                acc[0][b] = fmaf(wa.y, ev.y, acc[0][b]);
                acc[0][b] = fmaf(wa.z, ev.z, acc[0][b]);
                acc[0][b] = fmaf(wa.w, ev.w, acc[0][b]);
                acc[1][b] = fmaf(wb.x, ev.x, acc[1][b]);
                acc[1][b] = fmaf(wb.y, ev.y, acc[1][b]);
                acc[1][b] = fmaf(wb.z, ev.z, acc[1][b]);
                acc[1][b] = fmaf(wb.w, ev.w, acc[1][b]);
            }
        }
        #pragma unroll
        for (int b = 0; b < 4; ++b) {
            float a0 = acc[0][b], a1 = acc[1][b];
            H1[b * 128 + l]      = a0 / (1.0f + expf(-a0));   // SiLU
            H1[b * 128 + 64 + l] = a1 / (1.0f + expf(-a1));
        }
    }
    __syncthreads();

    // ---- layer 2: same mapping, W2/b2, H1 -> E (h2) ----
    {
        const f32x4* w0 = (const f32x4*)(W2 + l * 128);
        const f32x4* w1 = (const f32x4*)(W2 + (l + 64) * 128);
        float acc[2][4];
        float bv0 = b2[l], bv1 = b2[l + 64];
        #pragma unroll
        for (int b = 0; b < 4; ++b) { acc[0][b] = bv0; acc[1][b] = bv1; }
        #pragma unroll 8
        for (int k4 = 0; k4 < 32; ++k4) {
            f32x4 wa = w0[k4];
            f32x4 wb = w1[k4];
            #pragma unroll
            for (int b = 0; b < 4; ++b) {
                f32x4 ev = ((const f32x4*)(H1 + b * 128))[k4];
                acc[0][b] = fmaf(wa.x, ev.x, acc[0][b]);
                acc[0][b] = fmaf(wa.y, ev.y, acc[0][b]);
                acc[0][b] = fmaf(wa.z, ev.z, acc[0][b]);
                acc[0][b] = fmaf(wa.w, ev.w, acc[0][b]);
                acc[1][b] = fmaf(wb.x, ev.x, acc[1][b]);
                acc[1][b] = fmaf(wb.y, ev.y, acc[1][b]);
                acc[1][b] = fmaf(wb.z, ev.z, acc[1][b]);
                acc[1][b] = fmaf(wb.w, ev.w, acc[1][b]);
            }
        }
        #pragma unroll
        for (int b = 0; b < 4; ++b) {
            float a0 = acc[0][b], a1 = acc[1][b];
            E[b * 128 + l]      = a0 / (1.0f + expf(-a0));
            E[b * 128 + 64 + l] = a1 / (1.0f + expf(-a1));
        }
    }
    __syncthreads();

    // ---- tail: write ONLY row 0 of each image (4 x 512 B per wave).
    // idx p*64+l -> image idx>>5, f32x4 col idx&31; two coalesced 1 KB
    // store instructions per wave.
    #pragma unroll
    for (int p = 0; p < 2; ++p) {
        int idx = p * 64 + l;        // 0..127
        int b   = idx >> 5;          // image 0..3 within this wave
        int j4  = idx & 31;          // f32x4 column
        f32x4 v = *(const f32x4*)&E[b * 128 + j4 * 4];
        *(f32x4*)(out + (size_t)(base + b) * 16384 + j4 * 4) = v;
    }
}

// R12's proven broadcast kernel: one block per image; read row 0, write
// rows 1..127 (row 0 skipped -> no write race). Memset-shaped store stream.
__global__ __launch_bounds__(256) void k_bcast(float* __restrict__ out)
{
    const int tid = threadIdx.x;
    f32x4* d = (f32x4*)(out + (size_t)blockIdx.x * 16384);
    f32x4 v = d[tid & 31];                 // row 0 (written by k_mlp_lite)
    if (tid >= 32) d[tid] = v;             // chunk 0, rows 1..7
    #pragma unroll
    for (int c = 1; c < 16; ++c) {
        d[c * 256 + tid] = v;              // rows 8c .. 8c+7
    }
}

extern "C" void kernel_launch(void* const* d_in, const int* in_sizes, int n_in,
                              void* d_out, int out_size, void* d_ws, size_t ws_size,
                              hipStream_t stream) {
    const float* t  = (const float*)d_in[0];
    const float* W1 = (const float*)d_in[1];
    const float* b1 = (const float*)d_in[2];
    const float* W2 = (const float*)d_in[3];
    const float* b2 = (const float*)d_in[4];
    float* out = (float*)d_out;
    const int B = in_sizes[0];   // 8192

    k_mlp_lite<<<B / 4, 64, 0, stream>>>(t, W1, b1, W2, b2, out);
    k_bcast<<<B, 256, 0, stream>>>(out);
}

// Round 5
// 560.092 us; speedup vs baseline: 1.0193x; 1.0193x over previous
//
#include <hip/hip_runtime.h>
#include <math.h>

typedef float f32x4 __attribute__((ext_vector_type(4)));

// ---------------------------------------------------------------------------
// R16: R14's wave-independent fused kernel + NONTEMPORAL output stores.
//
// Evidence: five structurally different kernels (R11 fused-heavy, R12 split,
// R13 barrier-aligned, R14 wave-independent, R15 split-light) all land at
// dur_us 539-571, i.e. kernel-side ~200-230 us regardless of structure.
// Mandatory work = 537 MB output write -> every variant ran its store stream
// at ~2.5 TB/s. The runtime's fillBufferAligned sustains 6.3 TB/s of PURE
// writes on the same buffer. Difference: the fill uses streaming/nontemporal
// cache policy; our plain write-back global_store_dwordx4 allocate+evict
// 537 MB through 32 MB of L2. The output is never re-read on device ->
// nontemporal is exactly right.
//
// Single isolated change vs R14: the 64-store broadcast tail uses
// __builtin_nontemporal_store. All math byte-identical -> same absmax.
// ---------------------------------------------------------------------------
__global__ __launch_bounds__(64) void k_fused(
    const float* __restrict__ t,
    const float* __restrict__ W1, const float* __restrict__ b1,
    const float* __restrict__ W2, const float* __restrict__ b2,
    float* __restrict__ out)
{
    __shared__ __attribute__((aligned(16))) float E [4 * 128]; // emb -> h2
    __shared__ __attribute__((aligned(16))) float H1[4 * 128];

    const int l    = threadIdx.x;        // lane 0..63
    const int base = blockIdx.x * 4;     // 4 batches per wave

    // ---- embedding: lane l owns freq l; 4 batches ----
    {
        double a   = (double)l * (6.907755278982137 / 63.0);
        float freq = (float)exp(a);
        float ang  = 6.2831853071795865f * freq;
        #pragma unroll
        for (int b = 0; b < 4; ++b) {
            float ph = t[base + b] * ang;
            float sv, cv;
            sincosf(ph, &sv, &cv);
            E[b * 128 + l]      = sv;
            E[b * 128 + 64 + l] = cv;
        }
    }
    __syncthreads();   // 1-wave block: waitcnt only

    // ---- layer 1: neurons r0=l, r1=l+64 over 4 batches ----
    {
        const f32x4* w0 = (const f32x4*)(W1 + l * 128);
        const f32x4* w1 = (const f32x4*)(W1 + (l + 64) * 128);
        float acc[2][4];
        float bv0 = b1[l], bv1 = b1[l + 64];
        #pragma unroll
        for (int b = 0; b < 4; ++b) { acc[0][b] = bv0; acc[1][b] = bv1; }
        #pragma unroll 8
        for (int k4 = 0; k4 < 32; ++k4) {
            f32x4 wa = w0[k4];
            f32x4 wb = w1[k4];
            #pragma unroll
            for (int b = 0; b < 4; ++b) {
                f32x4 ev = ((const f32x4*)(E + b * 128))[k4];  // LDS broadcast
                acc[0][b] = fmaf(wa.x, ev.x, acc[0][b]);
                acc[0][b] = fmaf(wa.y, ev.y, acc[0][b]);
                acc[0][b] = fmaf(wa.z, ev.z, acc[0][b]);
                acc[0][b] = fmaf(wa.w, ev.w, acc[0][b]);
                acc[1][b] = fmaf(wb.x, ev.x, acc[1][b]);
                acc[1][b] = fmaf(wb.y, ev.y, acc[1][b]);
                acc[1][b] = fmaf(wb.z, ev.z, acc[1][b]);
                acc[1][b] = fmaf(wb.w, ev.w, acc[1][b]);
            }
        }
        #pragma unroll
        for (int b = 0; b < 4; ++b) {
            float a0 = acc[0][b], a1 = acc[1][b];
            H1[b * 128 + l]      = a0 / (1.0f + expf(-a0));   // SiLU
            H1[b * 128 + 64 + l] = a1 / (1.0f + expf(-a1));
        }
    }
    __syncthreads();

    // ---- layer 2: same mapping, W2/b2, H1 -> E (h2) ----
    {
        const f32x4* w0 = (const f32x4*)(W2 + l * 128);
        const f32x4* w1 = (const f32x4*)(W2 + (l + 64) * 128);
        float acc[2][4];
        float bv0 = b2[l], bv1 = b2[l + 64];
        #pragma unroll
        for (int b = 0; b < 4; ++b) { acc[0][b] = bv0; acc[1][b] = bv1; }
        #pragma unroll 8
        for (int k4 = 0; k4 < 32; ++k4) {
            f32x4 wa = w0[k4];
            f32x4 wb = w1[k4];
            #pragma unroll
            for (int b = 0; b < 4; ++b) {
                f32x4 ev = ((const f32x4*)(H1 + b * 128))[k4];
                acc[0][b] = fmaf(wa.x, ev.x, acc[0][b]);
                acc[0][b] = fmaf(wa.y, ev.y, acc[0][b]);
                acc[0][b] = fmaf(wa.z, ev.z, acc[0][b]);
                acc[0][b] = fmaf(wa.w, ev.w, acc[0][b]);
                acc[1][b] = fmaf(wb.x, ev.x, acc[1][b]);
                acc[1][b] = fmaf(wb.y, ev.y, acc[1][b]);
                acc[1][b] = fmaf(wb.z, ev.z, acc[1][b]);
                acc[1][b] = fmaf(wb.w, ev.w, acc[1][b]);
            }
        }
        #pragma unroll
        for (int b = 0; b < 4; ++b) {
            float a0 = acc[0][b], a1 = acc[1][b];
            E[b * 128 + l]      = a0 / (1.0f + expf(-a0));
            E[b * 128 + 64 + l] = a1 / (1.0f + expf(-a1));
        }
    }
    __syncthreads();

    // ---- store: 4 images x 64 KB, NONTEMPORAL (output never re-read on
    // device; bypass L2 write-allocate like the runtime's fill kernel).
    // Image = 4096 f32x4; lane writes chunks c*64+l; in-row column
    // ((c*64+l)&31 = l&31) invariant -> v loaded once per image.
    #pragma unroll
    for (int b = 0; b < 4; ++b) {
        f32x4 v  = *(const f32x4*)&E[b * 128 + (l & 31) * 4];
        f32x4* d = (f32x4*)(out + (size_t)(base + b) * 16384);
        #pragma unroll
        for (int c = 0; c < 64; ++c) {
            __builtin_nontemporal_store(v, d + c * 64 + l);
        }
    }
}

extern "C" void kernel_launch(void* const* d_in, const int* in_sizes, int n_in,
                              void* d_out, int out_size, void* d_ws, size_t ws_size,
                              hipStream_t stream) {
    const float* t  = (const float*)d_in[0];
    const float* W1 = (const float*)d_in[1];
    const float* b1 = (const float*)d_in[2];
    const float* W2 = (const float*)d_in[3];
    const float* b2 = (const float*)d_in[4];
    float* out = (float*)d_out;
    const int B = in_sizes[0];   // 8192

    k_fused<<<B / 4, 64, 0, stream>>>(t, W1, b1, W2, b2, out);
}